// Round 22
// baseline (355.617 us; speedup 1.0000x reference)
//
#include <hip/hip_runtime.h>

// Graphormer layer, MI355X round 22: r21 (242us) + TLP retest with the L2
// confounder removed — attn QT=32, grid 512 (2 blocks/CU, launch_bounds(512,4)),
// nt bias loads kept. K/V L2-resident so doubled K/V reads are cheap.
// N=4096, D=512, H=8, DH=64, F=2048. fp32 in/out, bf16 MFMA internally.

typedef float f32x4 __attribute__((ext_vector_type(4)));
typedef short s8v  __attribute__((ext_vector_type(8)));   // 8 bf16 in 4 VGPRs
typedef unsigned short u16;

#define MFMA16(a,b,c) __builtin_amdgcn_mfma_f32_16x16x32_bf16((a),(b),(c),0,0,0)

static constexpr int N  = 4096;
static constexpr int D  = 512;
static constexpr int H  = 8;
static constexpr int F  = 2048;
static constexpr int QKVW = 3 * D;       // 1536
static constexpr int NH   = N * H;       // 32768 (bias row stride in floats)
static constexpr int QT   = 32;          // q-rows per attn block
static constexpr int MS   = 4;           // m-splits
static constexpr int ATTN_LDS = 65536;   // bias dbuf: 2 x 32KB (transposed)

__device__ inline u16 f2bf(float f) {
  union { float f; unsigned u; } x; x.f = f;
  unsigned r = x.u + 0x7fffu + ((x.u >> 16) & 1u);
  return (u16)(r >> 16);
}
__device__ inline float bf2f(u16 u) {
  union { unsigned u; float f; } x; x.u = ((unsigned)u) << 16;
  return x.f;
}

typedef const unsigned __attribute__((address_space(1)))* gp_t;
typedef unsigned __attribute__((address_space(3)))* lp_t;
__device__ inline void gl_lds16(const void* g, void* l) {
  __builtin_amdgcn_global_load_lds((gp_t)g, (lp_t)l, 16, 0, 0);
}

// ---------------- LayerNorm: fp32 (N,512) -> bf16 (N,512) ----------------
__global__ __launch_bounds__(256) void ln_kernel(const float* __restrict__ x,
                                                 const float* __restrict__ g,
                                                 const float* __restrict__ b,
                                                 u16* __restrict__ out) {
  const int row  = blockIdx.x * 4 + (threadIdx.x >> 6);
  const int lane = threadIdx.x & 63;
  const float4* xr = (const float4*)(x + (size_t)row * D);
  float4 v0 = xr[lane], v1 = xr[64 + lane];
  float s  = v0.x + v0.y + v0.z + v0.w + v1.x + v1.y + v1.z + v1.w;
  float ss = v0.x*v0.x + v0.y*v0.y + v0.z*v0.z + v0.w*v0.w
           + v1.x*v1.x + v1.y*v1.y + v1.z*v1.z + v1.w*v1.w;
  for (int off = 1; off < 64; off <<= 1) {
    s  += __shfl_xor(s,  off);
    ss += __shfl_xor(ss, off);
  }
  const float mu   = s * (1.0f / D);
  const float var  = ss * (1.0f / D) - mu * mu;
  const float rstd = rsqrtf(var + 1e-5f);
  const float4* g4 = (const float4*)g;
  const float4* b4 = (const float4*)b;
  float4 g0 = g4[lane], g1 = g4[64 + lane];
  float4 b0 = b4[lane], b1 = b4[64 + lane];
  u16* orow = out + (size_t)row * D;
  ushort4 o0, o1;
  o0.x = f2bf((v0.x - mu) * rstd * g0.x + b0.x);
  o0.y = f2bf((v0.y - mu) * rstd * g0.y + b0.y);
  o0.z = f2bf((v0.z - mu) * rstd * g0.z + b0.z);
  o0.w = f2bf((v0.w - mu) * rstd * g0.w + b0.w);
  o1.x = f2bf((v1.x - mu) * rstd * g1.x + b1.x);
  o1.y = f2bf((v1.y - mu) * rstd * g1.y + b1.y);
  o1.z = f2bf((v1.z - mu) * rstd * g1.z + b1.z);
  o1.w = f2bf((v1.w - mu) * rstd * g1.w + b1.w);
  ((ushort4*)orow)[lane]      = o0;
  ((ushort4*)orow)[64 + lane] = o1;
}

// ------ ALL weight transposes in one launch (tiled 32x32, coalesced) -----
__global__ __launch_bounds__(256) void transpose_all(
    const float* __restrict__ wq, const float* __restrict__ wk,
    const float* __restrict__ wv, const float* __restrict__ wo,
    const float* __restrict__ w1, const float* __restrict__ w2,
    u16* __restrict__ WqkvT, u16* __restrict__ WoT,
    u16* __restrict__ W1T, u16* __restrict__ W2T) {
  __shared__ u16 tl[32][33];
  const int b = blockIdx.x;
  const float* src; u16* dst; int R, C, tb;
  if (b < 768)       { int m = b >> 8; tb = b & 255;
                       src = (m == 0) ? wq : (m == 1) ? wk : wv;
                       dst = WqkvT + m * D * D; R = D; C = D; }
  else if (b < 1024) { tb = b - 768;  src = wo; dst = WoT; R = D; C = D; }
  else if (b < 2048) { tb = b - 1024; src = w1; dst = W1T; R = D; C = F; }
  else               { tb = b - 2048; src = w2; dst = W2T; R = F; C = D; }
  const int tx = C / 32;
  const int cb = tb % tx, rb = tb / tx;
  const int c = threadIdx.x & 31, r8 = threadIdx.x >> 5;
#pragma unroll
  for (int i = 0; i < 4; i++) {
    int r = r8 + i * 8;
    tl[r][c] = f2bf(src[(size_t)(rb * 32 + r) * C + cb * 32 + c]);
  }
  __syncthreads();
#pragma unroll
  for (int i = 0; i < 4; i++) {
    int r = r8 + i * 8;
    dst[(size_t)(cb * 32 + r) * R + rb * 32 + c] = tl[c][r];
  }
}

__global__ void pack_bqkv(const float* __restrict__ bq, const float* __restrict__ bk,
                          const float* __restrict__ bv, float* __restrict__ bqkv) {
  int i = blockIdx.x * 256 + threadIdx.x;
  if (i < QKVW) bqkv[i] = (i < D) ? bq[i] : (i < 2 * D) ? bk[i - D] : bv[i - 2 * D];
}

// ---- K + V fragment tiles in one launch ------
__global__ void make_kvtiles(const u16* __restrict__ qkv,
                             u16* __restrict__ kt, u16* __restrict__ vt) {
  if (blockIdx.x < 1024) {
    int t = blockIdx.x * 256 + threadIdx.x;      // 262144 chunks
    int ln = t & 63, half = (t >> 6) & 1, h = (t >> 7) & 7, mt = t >> 10;
    int lr = ln & 15, lq = ln >> 4;
    const u16* src = qkv + (size_t)(mt * 16 + lr) * QKVW + D + h * 64 + half * 32 + lq * 8;
    *(int4*)(kt + (size_t)t * 8) = *(const int4*)src;
  } else {
    int t = (blockIdx.x - 1024) * 256 + threadIdx.x;
    int ln = t & 63, db = (t >> 6) & 3, h = (t >> 8) & 7, mt32 = t >> 11;
    int lr = ln & 15, lq = ln >> 4;
    s8v v;
#pragma unroll
    for (int e = 0; e < 8; e++) {
      int msrc = 4 * lq + 16 * (e >> 2) + (e & 3);
      v[e] = (short)qkv[(size_t)(mt32 * 32 + msrc) * QKVW + 2 * D + h * 64 + db * 16 + lr];
    }
    *(s8v*)(vt + (size_t)t * 8) = v;
  }
}

// ------- GEMM: C = A @ Bt^T (+epilogue), gl_lds staging, BM=128 ----------
template <int MODE>
__global__ __launch_bounds__(256) void gemm_bt(const u16* __restrict__ A,
                                               const u16* __restrict__ Bt,
                                               const float* __restrict__ bias,
                                               const float* __restrict__ res,
                                               void* __restrict__ outv,
                                               int M, int Nn, int K) {
  __shared__ __align__(16) u16 As[128 * 32];
  __shared__ __align__(16) u16 Bs[128 * 32];
  const int t = threadIdx.x;
  const int lane = t & 63, w = t >> 6;
  const int wr = w >> 1, wc = w & 1;
  const int lr = lane & 15, lq = lane >> 4;
  const int r0 = blockIdx.y * 128, c0 = blockIdx.x * 128;
  const int srow = lane >> 2, scc = (lane & 3) * 8;
  f32x4 acc[4][4] = {};
  for (int k0 = 0; k0 < K; k0 += 32) {
    __syncthreads();
#pragma unroll
    for (int s = w; s < 8; s += 4) {
      gl_lds16(&A[(size_t)(r0 + s * 16 + srow) * K + k0 + scc], &As[s * 512]);
      gl_lds16(&Bt[(size_t)(c0 + s * 16 + srow) * K + k0 + scc], &Bs[s * 512]);
    }
    __syncthreads();
    s8v af[4], bf[4];
#pragma unroll
    for (int m = 0; m < 4; m++) af[m] = *(const s8v*)&As[(wr * 64 + m * 16 + lr) * 32 + lq * 8];
#pragma unroll
    for (int n = 0; n < 4; n++) bf[n] = *(const s8v*)&Bs[(wc * 64 + n * 16 + lr) * 32 + lq * 8];
#pragma unroll
    for (int m = 0; m < 4; m++)
#pragma unroll
      for (int n = 0; n < 4; n++) acc[m][n] = MFMA16(af[m], bf[n], acc[m][n]);
  }
#pragma unroll
  for (int m = 0; m < 4; m++)
#pragma unroll
    for (int n = 0; n < 4; n++) {
      const int col = c0 + wc * 64 + n * 16 + lr;
      const float bcol = bias[col];
#pragma unroll
      for (int j = 0; j < 4; j++) {
        const int row = r0 + wr * 64 + m * 16 + lq * 4 + j;
        float v = acc[m][n][j] + bcol;
        if (MODE == 0) {
          ((u16*)outv)[(size_t)row * Nn + col] = f2bf(v);
        } else if (MODE == 1) {
          v = 0.5f * v * (1.0f + erff(v * 0.70710678118654752f));
          ((u16*)outv)[(size_t)row * Nn + col] = f2bf(v);
        } else {
          ((float*)outv)[(size_t)row * Nn + col] = v + res[(size_t)row * Nn + col];
        }
      }
    }
  (void)M;
}

// ---- GEMM BM=64 (full-occupancy path for Nn=512): f32 out = acc+bias+res.
__global__ __launch_bounds__(256) void gemm_bt64(const u16* __restrict__ A,
                                                 const u16* __restrict__ Bt,
                                                 const float* __restrict__ bias,
                                                 const float* __restrict__ res,
                                                 float* __restrict__ out,
                                                 int M, int Nn, int K) {
  __shared__ __align__(16) u16 As[64 * 32];
  __shared__ __align__(16) u16 Bs[128 * 32];
  const int t = threadIdx.x;
  const int lane = t & 63, w = t >> 6;
  const int wr = w >> 1, wc = w & 1;
  const int lr = lane & 15, lq = lane >> 4;
  const int r0 = blockIdx.y * 64, c0 = blockIdx.x * 128;
  const int srow = lane >> 2, scc = (lane & 3) * 8;
  f32x4 acc[2][4] = {};
  for (int k0 = 0; k0 < K; k0 += 32) {
    __syncthreads();
    gl_lds16(&A[(size_t)(r0 + w * 16 + srow) * K + k0 + scc], &As[w * 512]);
#pragma unroll
    for (int s = w; s < 8; s += 4)
      gl_lds16(&Bt[(size_t)(c0 + s * 16 + srow) * K + k0 + scc], &Bs[s * 512]);
    __syncthreads();
    s8v af[2], bf[4];
#pragma unroll
    for (int m = 0; m < 2; m++) af[m] = *(const s8v*)&As[(wr * 32 + m * 16 + lr) * 32 + lq * 8];
#pragma unroll
    for (int n = 0; n < 4; n++) bf[n] = *(const s8v*)&Bs[(wc * 64 + n * 16 + lr) * 32 + lq * 8];
#pragma unroll
    for (int m = 0; m < 2; m++)
#pragma unroll
      for (int n = 0; n < 4; n++) acc[m][n] = MFMA16(af[m], bf[n], acc[m][n]);
  }
#pragma unroll
  for (int m = 0; m < 2; m++)
#pragma unroll
    for (int n = 0; n < 4; n++) {
      const int col = c0 + wc * 64 + n * 16 + lr;
      const float bcol = bias[col];
#pragma unroll
      for (int j = 0; j < 4; j++) {
        const int row = r0 + wr * 32 + m * 16 + lq * 4 + j;
        out[(size_t)row * Nn + col] = acc[m][n][j] + bcol + res[(size_t)row * Nn + col];
      }
    }
  (void)M;
}

// ----------------------- flash attention + bias --------------------------
// grid 512 = (qb 128) x (ms 4), XCD-aware: ms=(bid&7)>>1, qb=((bid>>3)<<1)|(bid&1).
// 2 blocks/CU (2x32KB LDS each). 512 thr = 8 waves, wave = head; 2 qc; MT=32.
// Bias: NONTEMPORAL reg-staged (4 chunks/thread), transposed swizzled LDS
// [q][h][m^((q&7)<<2)], conflict-free b128 reads. sigma-PV zero-shuffle.
__global__ __launch_bounds__(512, 4) void attn_kernel(const u16* __restrict__ qkv,
                                                      const u16* __restrict__ kt,
                                                      const u16* __restrict__ vt,
                                                      const float* __restrict__ bias,
                                                      u16* __restrict__ ctxp,
                                                      float* __restrict__ ml) {
  extern __shared__ __align__(16) char smem[];
  const int tid = threadIdx.x, lane = tid & 63, h = tid >> 6;   // wave = head
  const int lr = lane & 15, lq = lane >> 4;
  const int bid = blockIdx.x;
  const int ms = (bid & 7) >> 1;
  const int qb = ((bid >> 3) << 1) | (bid & 1);    // 0..127 bijective
  const int q0 = qb * QT;
  const int mt32_0 = ms * 32;

  // bias staging: 2048 f32x4 chunks per tile; thread handles 4 (nt loads).
  f32x4 breg[4];
  auto load_bias = [&](int t) {
#pragma unroll
    for (int i = 0; i < 4; i++) {
      int g = i * 512 + tid;
      int q = g >> 6, cc = g & 63;           // q wave-uniform, cc = lane
      breg[i] = __builtin_nontemporal_load(
          (const f32x4*)(bias + (size_t)(q0 + q) * NH
            + (size_t)((mt32_0 + t) * 32 + (cc >> 1)) * H + (cc & 1) * 4));
    }
  };
  auto write_bias = [&](int buf) {
    float* bl = (float*)(smem + buf * 32768);
#pragma unroll
    for (int i = 0; i < 4; i++) {
      int g = i * 512 + tid;
      int q = g >> 6, cc = g & 63;
      int m = cc >> 1, h0 = (cc & 1) * 4;
      int mp = m ^ ((q & 7) << 2);
#pragma unroll
      for (int e = 0; e < 4; e++)
        bl[q * 256 + (h0 + e) * 32 + mp] = breg[i][e];
    }
  };

  // Q fragments (2 qc)
  s8v qf[2][2];
#pragma unroll
  for (int qc = 0; qc < 2; qc++) {
    const u16* qp = qkv + (size_t)(q0 + qc * 16 + lr) * QKVW + h * 64 + lq * 8;
    qf[qc][0] = *(const s8v*)qp;
    qf[qc][1] = *(const s8v*)(qp + 32);
  }

  f32x4 cacc[2][4] = {};
  float mrun[2] = {-1e30f, -1e30f}, lsum[2] = {0.0f, 0.0f};

  load_bias(0);
  write_bias(0);
  __syncthreads();

  for (int t = 0; t < 32; t++) {
    // K/V loads (L2-resident via XCD mapping; nt bias keeps them cached)
    const int mt = (mt32_0 + t) * 2;
    s8v kf[4];
    {
      const u16* kp0 = kt + ((size_t)(mt * 8 + h) * 2) * 512 + lane * 8;
      const u16* kp1 = kt + ((size_t)((mt + 1) * 8 + h) * 2) * 512 + lane * 8;
      kf[0] = *(const s8v*)kp0;
      kf[1] = *(const s8v*)(kp0 + 512);
      kf[2] = *(const s8v*)kp1;
      kf[3] = *(const s8v*)(kp1 + 512);
    }
    s8v vf[4];
    {
      const u16* vp = vt + ((size_t)((mt32_0 + t) * 8 + h) * 4) * 512 + lane * 8;
#pragma unroll
      for (int db = 0; db < 4; db++) vf[db] = *(const s8v*)(vp + (size_t)db * 512);
    }
    // issue next bias tile loads EARLY (latency hides under compute + TLP)
    if (t + 1 < 32) load_bias(t + 1);

    const float* bl = (const float*)(smem + (t & 1) * 32768);
#pragma unroll
    for (int qc = 0; qc < 2; qc++) {
      f32x4 s0 = {}, s1 = {};
      s0 = MFMA16(kf[0], qf[qc][0], s0);
      s0 = MFMA16(kf[1], qf[qc][1], s0);
      s1 = MFMA16(kf[2], qf[qc][0], s1);
      s1 = MFMA16(kf[3], qf[qc][1], s1);
      const int q = qc * 16 + lr;
      const int sw = (q & 7) << 2;
      const float* blq = bl + q * 256 + h * 32;
      float p[8];
      float tmax = -1e30f;
#pragma unroll
      for (int s = 0; s < 2; s++) {
        f32x4 b4 = *(const f32x4*)(blq + ((s * 16 + lq * 4) ^ sw));
#pragma unroll
        for (int j = 0; j < 4; j++) {
          const float sv = (s ? s1[j] : s0[j]) * 0.125f + b4[j];
          p[s * 4 + j] = sv;
          tmax = fmaxf(tmax, sv);
        }
      }
      tmax = fmaxf(tmax, __shfl_xor(tmax, 16));
      tmax = fmaxf(tmax, __shfl_xor(tmax, 32));
      if (!__all(tmax <= mrun[qc])) {          // T13: skip no-op rescale
        float mnew = fmaxf(mrun[qc], tmax);
        float sc = __expf(mrun[qc] - mnew);
        mrun[qc] = mnew;
        lsum[qc] *= sc;
#pragma unroll
        for (int db = 0; db < 4; db++) cacc[qc][db] *= sc;
      }
      float psum = 0.0f;
#pragma unroll
      for (int j = 0; j < 8; j++) { p[j] = __expf(p[j] - mrun[qc]); psum += p[j]; }
      lsum[qc] += psum;
      // sigma-layout: identity packing, zero shuffles
      union { unsigned u[4]; s8v v; } pa;
      asm("v_cvt_pk_bf16_f32 %0, %1, %2" : "=v"(pa.u[0]) : "v"(p[0]), "v"(p[1]));
      asm("v_cvt_pk_bf16_f32 %0, %1, %2" : "=v"(pa.u[1]) : "v"(p[2]), "v"(p[3]));
      asm("v_cvt_pk_bf16_f32 %0, %1, %2" : "=v"(pa.u[2]) : "v"(p[4]), "v"(p[5]));
      asm("v_cvt_pk_bf16_f32 %0, %1, %2" : "=v"(pa.u[3]) : "v"(p[6]), "v"(p[7]));
#pragma unroll
      for (int db = 0; db < 4; db++) cacc[qc][db] = MFMA16(vf[db], pa.v, cacc[qc][db]);
    }
    // write next tile; one barrier per iter
    if (t + 1 < 32) write_bias((t + 1) & 1);
    __syncthreads();
  }

  // ---- finalize: reduce lsum over lq; write bf16 partials ----
#pragma unroll
  for (int qc = 0; qc < 2; qc++) {
    lsum[qc] += __shfl_xor(lsum[qc], 16);
    lsum[qc] += __shfl_xor(lsum[qc], 32);
  }
  if (lq == 0) {
#pragma unroll
    for (int qc = 0; qc < 2; qc++) {
      float2 v = make_float2(mrun[qc], lsum[qc]);
      *(float2*)(ml + (((size_t)ms * N + q0 + qc * 16 + lr) * H + h) * 2) = v;
    }
  }
#pragma unroll
  for (int qc = 0; qc < 2; qc++)
#pragma unroll
    for (int db = 0; db < 4; db++) {
      const size_t q = q0 + qc * 16 + lr;
      ushort4 r4;
      r4.x = f2bf(cacc[qc][db][0]);
      r4.y = f2bf(cacc[qc][db][1]);
      r4.z = f2bf(cacc[qc][db][2]);
      r4.w = f2bf(cacc[qc][db][3]);
      *(ushort4*)(ctxp + ((size_t)ms * N + q) * D + h * 64 + db * 16 + lq * 4) = r4;
    }
}

// ---- merge the 4 m-split bf16 partials -> ctx bf16 (N,512) ----
__global__ __launch_bounds__(256) void attn_merge(const u16* __restrict__ ctxp,
                                                  const float* __restrict__ ml,
                                                  u16* __restrict__ ctx) {
  int idx = blockIdx.x * 256 + threadIdx.x;     // N * 128
  int q = idx >> 7, c = idx & 127;
  int d0 = c * 4, h = c >> 4;
  float m_[MS], l_[MS], M = -1e30f;
#pragma unroll
  for (int s = 0; s < MS; s++) {
    float2 v = *(const float2*)(ml + (((size_t)s * N + q) * H + h) * 2);
    m_[s] = v.x; l_[s] = v.y;
    M = fmaxf(M, v.x);
  }
  float L = 0.0f, w_[MS];
#pragma unroll
  for (int s = 0; s < MS; s++) { w_[s] = __expf(m_[s] - M); L += l_[s] * w_[s]; }
  const float inv = 1.0f / L;
  float o0 = 0.0f, o1 = 0.0f, o2 = 0.0f, o3 = 0.0f;
#pragma unroll
  for (int s = 0; s < MS; s++) {
    ushort4 pv = *(const ushort4*)(ctxp + ((size_t)s * N + q) * D + d0);
    o0 += bf2f(pv.x) * w_[s];
    o1 += bf2f(pv.y) * w_[s];
    o2 += bf2f(pv.z) * w_[s];
    o3 += bf2f(pv.w) * w_[s];
  }
  ushort4 r;
  r.x = f2bf(o0 * inv); r.y = f2bf(o1 * inv);
  r.z = f2bf(o2 * inv); r.w = f2bf(o3 * inv);
  *(ushort4*)(ctx + (size_t)q * D + d0) = r;
}

// ------------------------------- launch ----------------------------------
extern "C" void kernel_launch(void* const* d_in, const int* in_sizes, int n_in,
                              void* d_out, int out_size, void* d_ws, size_t ws_size,
                              hipStream_t stream) {
  const float* x    = (const float*)d_in[0];
  const float* abias= (const float*)d_in[1];
  const float* ln1g = (const float*)d_in[2];
  const float* ln1b = (const float*)d_in[3];
  const float* wq   = (const float*)d_in[4];
  const float* bq   = (const float*)d_in[5];
  const float* wk   = (const float*)d_in[6];
  const float* bk   = (const float*)d_in[7];
  const float* wv   = (const float*)d_in[8];
  const float* bv   = (const float*)d_in[9];
  const float* wo   = (const float*)d_in[10];
  const float* bo   = (const float*)d_in[11];
  const float* ln2g = (const float*)d_in[12];
  const float* ln2b = (const float*)d_in[13];
  const float* w1   = (const float*)d_in[14];
  const float* b1   = (const float*)d_in[15];
  const float* w2   = (const float*)d_in[16];
  const float* b2   = (const float*)d_in[17];
  float* out = (float*)d_out;

  char* ws = (char*)d_ws;
  size_t off = 0;
  auto alloc = [&](size_t bytes) { size_t o = off; off = (off + bytes + 255) & ~(size_t)255; return (void*)(ws + o); };
  u16*   xn    = (u16*)alloc((size_t)N * D * 2);
  u16*   qkv   = (u16*)alloc((size_t)N * QKVW * 2);
  u16*   ktl   = (u16*)alloc((size_t)N * D * 2);
  u16*   vtl   = (u16*)alloc((size_t)N * D * 2);
  u16*   ctx   = (u16*)alloc((size_t)N * D * 2);
  float* x2    = (float*)alloc((size_t)N * D * 4);
  u16*   xn2   = (u16*)alloc((size_t)N * D * 2);
  u16*   hb    = (u16*)alloc((size_t)N * F * 2);
  u16*   WqkvT = (u16*)alloc((size_t)QKVW * D * 2);
  u16*   WoT   = (u16*)alloc((size_t)D * D * 2);
  u16*   W1T   = (u16*)alloc((size_t)F * D * 2);
  u16*   W2T   = (u16*)alloc((size_t)D * F * 2);
  float* bqkv  = (float*)alloc((size_t)QKVW * 4);
  u16*   ctxp  = (u16*)alloc((size_t)MS * N * D * 2);     // 16 MB bf16 partials
  float* ml    = (float*)alloc((size_t)MS * N * H * 2 * 4);

  hipFuncSetAttribute((const void*)attn_kernel,
                      hipFuncAttributeMaxDynamicSharedMemorySize, ATTN_LDS);

  // weight prep: ONE transpose launch + bias pack
  transpose_all<<<3072, 256, 0, stream>>>(wq, wk, wv, wo, w1, w2,
                                          WqkvT, WoT, W1T, W2T);
  pack_bqkv<<<(QKVW + 255) / 256, 256, 0, stream>>>(bq, bk, bv, bqkv);

  // LN1 -> QKV
  ln_kernel<<<N / 4, 256, 0, stream>>>(x, ln1g, ln1b, xn);
  gemm_bt<0><<<dim3(QKVW / 128, N / 128), 256, 0, stream>>>(xn, WqkvT, bqkv, nullptr, qkv, N, QKVW, D);
  // K/V fragment tiles (one launch)
  make_kvtiles<<<2048, 256, 0, stream>>>(qkv, ktl, vtl);
  // attention: 512 blocks (XCD-mapped, 2/CU), then merge
  attn_kernel<<<(N / QT) * MS, 512, ATTN_LDS, stream>>>(qkv, ktl, vtl, abias, ctxp, ml);
  attn_merge<<<(N * 128) / 256, 256, 0, stream>>>(ctxp, ml, ctx);
  // O proj + residual -> x2 (fp32), full-occupancy BM=64
  gemm_bt64<<<dim3(D / 128, N / 64), 256, 0, stream>>>(ctx, WoT, bo, x, x2, N, D, D);
  // LN2 -> FFN
  ln_kernel<<<N / 4, 256, 0, stream>>>(x2, ln2g, ln2b, xn2);
  gemm_bt<1><<<dim3(F / 128, N / 128), 256, 0, stream>>>(xn2, W1T, b1, nullptr, hb, N, F, D);
  gemm_bt64<<<dim3(D / 128, N / 64), 256, 0, stream>>>(hb, W2T, b2, x2, out, N, D, F);
  (void)in_sizes; (void)n_in; (void)out_size; (void)ws_size;
}

// Round 23
// 241.890 us; speedup vs baseline: 1.4702x; 1.4702x over previous
//
#include <hip/hip_runtime.h>

// Graphormer layer, MI355X FINAL (= round 21, 242us): QT=64/MS=4 attention,
// XCD-aware mapping, nontemporal bias stream (L2 reserved for K/V),
// transposed conflict-free bias LDS, sigma-PV zero-shuffle, bf16 partials,
// gl_lds GEMMs, fused transposes/tiles.
// N=4096, D=512, H=8, DH=64, F=2048. fp32 in/out, bf16 MFMA internally.

typedef float f32x4 __attribute__((ext_vector_type(4)));
typedef short s8v  __attribute__((ext_vector_type(8)));   // 8 bf16 in 4 VGPRs
typedef unsigned short u16;

#define MFMA16(a,b,c) __builtin_amdgcn_mfma_f32_16x16x32_bf16((a),(b),(c),0,0,0)

static constexpr int N  = 4096;
static constexpr int D  = 512;
static constexpr int H  = 8;
static constexpr int F  = 2048;
static constexpr int QKVW = 3 * D;       // 1536
static constexpr int NH   = N * H;       // 32768 (bias row stride in floats)
static constexpr int QT   = 64;          // q-rows per attn block
static constexpr int MS   = 4;           // m-splits
static constexpr int ATTN_LDS = 131072;  // bias dbuf: 2 x 64KB (transposed)

__device__ inline u16 f2bf(float f) {
  union { float f; unsigned u; } x; x.f = f;
  unsigned r = x.u + 0x7fffu + ((x.u >> 16) & 1u);
  return (u16)(r >> 16);
}
__device__ inline float bf2f(u16 u) {
  union { unsigned u; float f; } x; x.u = ((unsigned)u) << 16;
  return x.f;
}

typedef const unsigned __attribute__((address_space(1)))* gp_t;
typedef unsigned __attribute__((address_space(3)))* lp_t;
__device__ inline void gl_lds16(const void* g, void* l) {
  __builtin_amdgcn_global_load_lds((gp_t)g, (lp_t)l, 16, 0, 0);
}

// ---------------- LayerNorm: fp32 (N,512) -> bf16 (N,512) ----------------
__global__ __launch_bounds__(256) void ln_kernel(const float* __restrict__ x,
                                                 const float* __restrict__ g,
                                                 const float* __restrict__ b,
                                                 u16* __restrict__ out) {
  const int row  = blockIdx.x * 4 + (threadIdx.x >> 6);
  const int lane = threadIdx.x & 63;
  const float4* xr = (const float4*)(x + (size_t)row * D);
  float4 v0 = xr[lane], v1 = xr[64 + lane];
  float s  = v0.x + v0.y + v0.z + v0.w + v1.x + v1.y + v1.z + v1.w;
  float ss = v0.x*v0.x + v0.y*v0.y + v0.z*v0.z + v0.w*v0.w
           + v1.x*v1.x + v1.y*v1.y + v1.z*v1.z + v1.w*v1.w;
  for (int off = 1; off < 64; off <<= 1) {
    s  += __shfl_xor(s,  off);
    ss += __shfl_xor(ss, off);
  }
  const float mu   = s * (1.0f / D);
  const float var  = ss * (1.0f / D) - mu * mu;
  const float rstd = rsqrtf(var + 1e-5f);
  const float4* g4 = (const float4*)g;
  const float4* b4 = (const float4*)b;
  float4 g0 = g4[lane], g1 = g4[64 + lane];
  float4 b0 = b4[lane], b1 = b4[64 + lane];
  u16* orow = out + (size_t)row * D;
  ushort4 o0, o1;
  o0.x = f2bf((v0.x - mu) * rstd * g0.x + b0.x);
  o0.y = f2bf((v0.y - mu) * rstd * g0.y + b0.y);
  o0.z = f2bf((v0.z - mu) * rstd * g0.z + b0.z);
  o0.w = f2bf((v0.w - mu) * rstd * g0.w + b0.w);
  o1.x = f2bf((v1.x - mu) * rstd * g1.x + b1.x);
  o1.y = f2bf((v1.y - mu) * rstd * g1.y + b1.y);
  o1.z = f2bf((v1.z - mu) * rstd * g1.z + b1.z);
  o1.w = f2bf((v1.w - mu) * rstd * g1.w + b1.w);
  ((ushort4*)orow)[lane]      = o0;
  ((ushort4*)orow)[64 + lane] = o1;
}

// ------ ALL weight transposes in one launch (tiled 32x32, coalesced) -----
__global__ __launch_bounds__(256) void transpose_all(
    const float* __restrict__ wq, const float* __restrict__ wk,
    const float* __restrict__ wv, const float* __restrict__ wo,
    const float* __restrict__ w1, const float* __restrict__ w2,
    u16* __restrict__ WqkvT, u16* __restrict__ WoT,
    u16* __restrict__ W1T, u16* __restrict__ W2T) {
  __shared__ u16 tl[32][33];
  const int b = blockIdx.x;
  const float* src; u16* dst; int R, C, tb;
  if (b < 768)       { int m = b >> 8; tb = b & 255;
                       src = (m == 0) ? wq : (m == 1) ? wk : wv;
                       dst = WqkvT + m * D * D; R = D; C = D; }
  else if (b < 1024) { tb = b - 768;  src = wo; dst = WoT; R = D; C = D; }
  else if (b < 2048) { tb = b - 1024; src = w1; dst = W1T; R = D; C = F; }
  else               { tb = b - 2048; src = w2; dst = W2T; R = F; C = D; }
  const int tx = C / 32;
  const int cb = tb % tx, rb = tb / tx;
  const int c = threadIdx.x & 31, r8 = threadIdx.x >> 5;
#pragma unroll
  for (int i = 0; i < 4; i++) {
    int r = r8 + i * 8;
    tl[r][c] = f2bf(src[(size_t)(rb * 32 + r) * C + cb * 32 + c]);
  }
  __syncthreads();
#pragma unroll
  for (int i = 0; i < 4; i++) {
    int r = r8 + i * 8;
    dst[(size_t)(cb * 32 + r) * R + rb * 32 + c] = tl[c][r];
  }
}

__global__ void pack_bqkv(const float* __restrict__ bq, const float* __restrict__ bk,
                          const float* __restrict__ bv, float* __restrict__ bqkv) {
  int i = blockIdx.x * 256 + threadIdx.x;
  if (i < QKVW) bqkv[i] = (i < D) ? bq[i] : (i < 2 * D) ? bk[i - D] : bv[i - 2 * D];
}

// ---- K + V fragment tiles in one launch ------
__global__ void make_kvtiles(const u16* __restrict__ qkv,
                             u16* __restrict__ kt, u16* __restrict__ vt) {
  if (blockIdx.x < 1024) {
    int t = blockIdx.x * 256 + threadIdx.x;      // 262144 chunks
    int ln = t & 63, half = (t >> 6) & 1, h = (t >> 7) & 7, mt = t >> 10;
    int lr = ln & 15, lq = ln >> 4;
    const u16* src = qkv + (size_t)(mt * 16 + lr) * QKVW + D + h * 64 + half * 32 + lq * 8;
    *(int4*)(kt + (size_t)t * 8) = *(const int4*)src;
  } else {
    int t = (blockIdx.x - 1024) * 256 + threadIdx.x;
    int ln = t & 63, db = (t >> 6) & 3, h = (t >> 8) & 7, mt32 = t >> 11;
    int lr = ln & 15, lq = ln >> 4;
    s8v v;
#pragma unroll
    for (int e = 0; e < 8; e++) {
      int msrc = 4 * lq + 16 * (e >> 2) + (e & 3);
      v[e] = (short)qkv[(size_t)(mt32 * 32 + msrc) * QKVW + 2 * D + h * 64 + db * 16 + lr];
    }
    *(s8v*)(vt + (size_t)t * 8) = v;
  }
}

// ------- GEMM: C = A @ Bt^T (+epilogue), gl_lds staging, BM=128 ----------
template <int MODE>
__global__ __launch_bounds__(256) void gemm_bt(const u16* __restrict__ A,
                                               const u16* __restrict__ Bt,
                                               const float* __restrict__ bias,
                                               const float* __restrict__ res,
                                               void* __restrict__ outv,
                                               int M, int Nn, int K) {
  __shared__ __align__(16) u16 As[128 * 32];
  __shared__ __align__(16) u16 Bs[128 * 32];
  const int t = threadIdx.x;
  const int lane = t & 63, w = t >> 6;
  const int wr = w >> 1, wc = w & 1;
  const int lr = lane & 15, lq = lane >> 4;
  const int r0 = blockIdx.y * 128, c0 = blockIdx.x * 128;
  const int srow = lane >> 2, scc = (lane & 3) * 8;
  f32x4 acc[4][4] = {};
  for (int k0 = 0; k0 < K; k0 += 32) {
    __syncthreads();
#pragma unroll
    for (int s = w; s < 8; s += 4) {
      gl_lds16(&A[(size_t)(r0 + s * 16 + srow) * K + k0 + scc], &As[s * 512]);
      gl_lds16(&Bt[(size_t)(c0 + s * 16 + srow) * K + k0 + scc], &Bs[s * 512]);
    }
    __syncthreads();
    s8v af[4], bf[4];
#pragma unroll
    for (int m = 0; m < 4; m++) af[m] = *(const s8v*)&As[(wr * 64 + m * 16 + lr) * 32 + lq * 8];
#pragma unroll
    for (int n = 0; n < 4; n++) bf[n] = *(const s8v*)&Bs[(wc * 64 + n * 16 + lr) * 32 + lq * 8];
#pragma unroll
    for (int m = 0; m < 4; m++)
#pragma unroll
      for (int n = 0; n < 4; n++) acc[m][n] = MFMA16(af[m], bf[n], acc[m][n]);
  }
#pragma unroll
  for (int m = 0; m < 4; m++)
#pragma unroll
    for (int n = 0; n < 4; n++) {
      const int col = c0 + wc * 64 + n * 16 + lr;
      const float bcol = bias[col];
#pragma unroll
      for (int j = 0; j < 4; j++) {
        const int row = r0 + wr * 64 + m * 16 + lq * 4 + j;
        float v = acc[m][n][j] + bcol;
        if (MODE == 0) {
          ((u16*)outv)[(size_t)row * Nn + col] = f2bf(v);
        } else if (MODE == 1) {
          v = 0.5f * v * (1.0f + erff(v * 0.70710678118654752f));
          ((u16*)outv)[(size_t)row * Nn + col] = f2bf(v);
        } else {
          ((float*)outv)[(size_t)row * Nn + col] = v + res[(size_t)row * Nn + col];
        }
      }
    }
  (void)M;
}

// ---- GEMM BM=64 (full-occupancy path for Nn=512): f32 out = acc+bias+res.
__global__ __launch_bounds__(256) void gemm_bt64(const u16* __restrict__ A,
                                                 const u16* __restrict__ Bt,
                                                 const float* __restrict__ bias,
                                                 const float* __restrict__ res,
                                                 float* __restrict__ out,
                                                 int M, int Nn, int K) {
  __shared__ __align__(16) u16 As[64 * 32];
  __shared__ __align__(16) u16 Bs[128 * 32];
  const int t = threadIdx.x;
  const int lane = t & 63, w = t >> 6;
  const int wr = w >> 1, wc = w & 1;
  const int lr = lane & 15, lq = lane >> 4;
  const int r0 = blockIdx.y * 64, c0 = blockIdx.x * 128;
  const int srow = lane >> 2, scc = (lane & 3) * 8;
  f32x4 acc[2][4] = {};
  for (int k0 = 0; k0 < K; k0 += 32) {
    __syncthreads();
    gl_lds16(&A[(size_t)(r0 + w * 16 + srow) * K + k0 + scc], &As[w * 512]);
#pragma unroll
    for (int s = w; s < 8; s += 4)
      gl_lds16(&Bt[(size_t)(c0 + s * 16 + srow) * K + k0 + scc], &Bs[s * 512]);
    __syncthreads();
    s8v af[2], bf[4];
#pragma unroll
    for (int m = 0; m < 2; m++) af[m] = *(const s8v*)&As[(wr * 32 + m * 16 + lr) * 32 + lq * 8];
#pragma unroll
    for (int n = 0; n < 4; n++) bf[n] = *(const s8v*)&Bs[(wc * 64 + n * 16 + lr) * 32 + lq * 8];
#pragma unroll
    for (int m = 0; m < 2; m++)
#pragma unroll
      for (int n = 0; n < 4; n++) acc[m][n] = MFMA16(af[m], bf[n], acc[m][n]);
  }
#pragma unroll
  for (int m = 0; m < 2; m++)
#pragma unroll
    for (int n = 0; n < 4; n++) {
      const int col = c0 + wc * 64 + n * 16 + lr;
      const float bcol = bias[col];
#pragma unroll
      for (int j = 0; j < 4; j++) {
        const int row = r0 + wr * 32 + m * 16 + lq * 4 + j;
        out[(size_t)row * Nn + col] = acc[m][n][j] + bcol + res[(size_t)row * Nn + col];
      }
    }
  (void)M;
}

// ----------------------- flash attention + bias --------------------------
// grid 256, XCD-aware: ms = (bid&7)>>1, qb = ((bid>>3)<<1)|(bid&1).
// 512 thr = 8 waves, wave = head. 4 qc x 16 q; MT=32 full-K PV.
// Bias: NONTEMPORAL reg-staged loads (read-once stream, L2 reserved for K/V),
// transposed swizzled LDS [q][h][m^((q&7)<<2)], conflict-free b128 reads.
__global__ __launch_bounds__(512, 2) void attn_kernel(const u16* __restrict__ qkv,
                                                      const u16* __restrict__ kt,
                                                      const u16* __restrict__ vt,
                                                      const float* __restrict__ bias,
                                                      u16* __restrict__ ctxp,
                                                      float* __restrict__ ml) {
  extern __shared__ __align__(16) char smem[];
  const int tid = threadIdx.x, lane = tid & 63, h = tid >> 6;   // wave = head
  const int lr = lane & 15, lq = lane >> 4;
  const int bid = blockIdx.x;
  const int ms = (bid & 7) >> 1;
  const int qb = ((bid >> 3) << 1) | (bid & 1);
  const int q0 = qb * QT;
  const int mt32_0 = ms * 32;

  // bias staging: 4096 f32x4 chunks per tile; thread handles 8 (nt loads).
  f32x4 breg[8];
  auto load_bias = [&](int t) {
#pragma unroll
    for (int i = 0; i < 8; i++) {
      int g = i * 512 + tid;
      int q = g >> 6, cc = g & 63;           // q wave-uniform, cc = lane
      breg[i] = __builtin_nontemporal_load(
          (const f32x4*)(bias + (size_t)(q0 + q) * NH
            + (size_t)((mt32_0 + t) * 32 + (cc >> 1)) * H + (cc & 1) * 4));
    }
  };
  auto write_bias = [&](int buf) {
    float* bl = (float*)(smem + buf * 65536);
#pragma unroll
    for (int i = 0; i < 8; i++) {
      int g = i * 512 + tid;
      int q = g >> 6, cc = g & 63;
      int m = cc >> 1, h0 = (cc & 1) * 4;
      int mp = m ^ ((q & 7) << 2);
#pragma unroll
      for (int e = 0; e < 4; e++)
        bl[q * 256 + (h0 + e) * 32 + mp] = breg[i][e];
    }
  };

  // Q fragments
  s8v qf[4][2];
#pragma unroll
  for (int qc = 0; qc < 4; qc++) {
    const u16* qp = qkv + (size_t)(q0 + qc * 16 + lr) * QKVW + h * 64 + lq * 8;
    qf[qc][0] = *(const s8v*)qp;
    qf[qc][1] = *(const s8v*)(qp + 32);
  }

  f32x4 cacc[4][4] = {};
  float mrun[4], lsum[4];
#pragma unroll
  for (int qc = 0; qc < 4; qc++) { mrun[qc] = -1e30f; lsum[qc] = 0.0f; }

  load_bias(0);
  write_bias(0);
  __syncthreads();

  for (int t = 0; t < 32; t++) {
    // K/V loads (L2-resident via XCD mapping)
    const int mt = (mt32_0 + t) * 2;
    s8v kf[4];
    {
      const u16* kp0 = kt + ((size_t)(mt * 8 + h) * 2) * 512 + lane * 8;
      const u16* kp1 = kt + ((size_t)((mt + 1) * 8 + h) * 2) * 512 + lane * 8;
      kf[0] = *(const s8v*)kp0;
      kf[1] = *(const s8v*)(kp0 + 512);
      kf[2] = *(const s8v*)kp1;
      kf[3] = *(const s8v*)(kp1 + 512);
    }
    s8v vf[4];
    {
      const u16* vp = vt + ((size_t)((mt32_0 + t) * 8 + h) * 4) * 512 + lane * 8;
#pragma unroll
      for (int db = 0; db < 4; db++) vf[db] = *(const s8v*)(vp + (size_t)db * 512);
    }
    // issue next bias tile loads EARLY (latency hides under compute, T14)
    if (t + 1 < 32) load_bias(t + 1);

    const float* bl = (const float*)(smem + (t & 1) * 65536);
#pragma unroll
    for (int qc = 0; qc < 4; qc++) {
      f32x4 s0 = {}, s1 = {};
      s0 = MFMA16(kf[0], qf[qc][0], s0);
      s0 = MFMA16(kf[1], qf[qc][1], s0);
      s1 = MFMA16(kf[2], qf[qc][0], s1);
      s1 = MFMA16(kf[3], qf[qc][1], s1);
      const int q = qc * 16 + lr;
      const int sw = (q & 7) << 2;
      const float* blq = bl + q * 256 + h * 32;
      float p[8];
      float tmax = -1e30f;
#pragma unroll
      for (int s = 0; s < 2; s++) {
        f32x4 b4 = *(const f32x4*)(blq + ((s * 16 + lq * 4) ^ sw));
#pragma unroll
        for (int j = 0; j < 4; j++) {
          const float sv = (s ? s1[j] : s0[j]) * 0.125f + b4[j];
          p[s * 4 + j] = sv;
          tmax = fmaxf(tmax, sv);
        }
      }
      tmax = fmaxf(tmax, __shfl_xor(tmax, 16));
      tmax = fmaxf(tmax, __shfl_xor(tmax, 32));
      if (!__all(tmax <= mrun[qc])) {          // T13: skip no-op rescale
        float mnew = fmaxf(mrun[qc], tmax);
        float sc = __expf(mrun[qc] - mnew);
        mrun[qc] = mnew;
        lsum[qc] *= sc;
#pragma unroll
        for (int db = 0; db < 4; db++) cacc[qc][db] *= sc;
      }
      float psum = 0.0f;
#pragma unroll
      for (int j = 0; j < 8; j++) { p[j] = __expf(p[j] - mrun[qc]); psum += p[j]; }
      lsum[qc] += psum;
      // sigma-layout: identity packing, zero shuffles
      union { unsigned u[4]; s8v v; } pa;
      asm("v_cvt_pk_bf16_f32 %0, %1, %2" : "=v"(pa.u[0]) : "v"(p[0]), "v"(p[1]));
      asm("v_cvt_pk_bf16_f32 %0, %1, %2" : "=v"(pa.u[1]) : "v"(p[2]), "v"(p[3]));
      asm("v_cvt_pk_bf16_f32 %0, %1, %2" : "=v"(pa.u[2]) : "v"(p[4]), "v"(p[5]));
      asm("v_cvt_pk_bf16_f32 %0, %1, %2" : "=v"(pa.u[3]) : "v"(p[6]), "v"(p[7]));
#pragma unroll
      for (int db = 0; db < 4; db++) cacc[qc][db] = MFMA16(vf[db], pa.v, cacc[qc][db]);
    }
    // write next tile (compiler inserts vmcnt for breg); one barrier per iter
    if (t + 1 < 32) write_bias((t + 1) & 1);
    __syncthreads();
  }

  // ---- finalize: reduce lsum over lq; write bf16 partials ----
#pragma unroll
  for (int qc = 0; qc < 4; qc++) {
    lsum[qc] += __shfl_xor(lsum[qc], 16);
    lsum[qc] += __shfl_xor(lsum[qc], 32);
  }
  if (lq == 0) {
#pragma unroll
    for (int qc = 0; qc < 4; qc++) {
      float2 v = make_float2(mrun[qc], lsum[qc]);
      *(float2*)(ml + (((size_t)ms * N + q0 + qc * 16 + lr) * H + h) * 2) = v;
    }
  }
#pragma unroll
  for (int qc = 0; qc < 4; qc++)
#pragma unroll
    for (int db = 0; db < 4; db++) {
      const size_t q = q0 + qc * 16 + lr;
      ushort4 r4;
      r4.x = f2bf(cacc[qc][db][0]);
      r4.y = f2bf(cacc[qc][db][1]);
      r4.z = f2bf(cacc[qc][db][2]);
      r4.w = f2bf(cacc[qc][db][3]);
      *(ushort4*)(ctxp + ((size_t)ms * N + q) * D + h * 64 + db * 16 + lq * 4) = r4;
    }
}

// ---- merge the 4 m-split bf16 partials -> ctx bf16 (N,512) ----
__global__ __launch_bounds__(256) void attn_merge(const u16* __restrict__ ctxp,
                                                  const float* __restrict__ ml,
                                                  u16* __restrict__ ctx) {
  int idx = blockIdx.x * 256 + threadIdx.x;     // N * 128
  int q = idx >> 7, c = idx & 127;
  int d0 = c * 4, h = c >> 4;
  float m_[MS], l_[MS], M = -1e30f;
#pragma unroll
  for (int s = 0; s < MS; s++) {
    float2 v = *(const float2*)(ml + (((size_t)s * N + q) * H + h) * 2);
    m_[s] = v.x; l_[s] = v.y;
    M = fmaxf(M, v.x);
  }
  float L = 0.0f, w_[MS];
#pragma unroll
  for (int s = 0; s < MS; s++) { w_[s] = __expf(m_[s] - M); L += l_[s] * w_[s]; }
  const float inv = 1.0f / L;
  float o0 = 0.0f, o1 = 0.0f, o2 = 0.0f, o3 = 0.0f;
#pragma unroll
  for (int s = 0; s < MS; s++) {
    ushort4 pv = *(const ushort4*)(ctxp + ((size_t)s * N + q) * D + d0);
    o0 += bf2f(pv.x) * w_[s];
    o1 += bf2f(pv.y) * w_[s];
    o2 += bf2f(pv.z) * w_[s];
    o3 += bf2f(pv.w) * w_[s];
  }
  ushort4 r;
  r.x = f2bf(o0 * inv); r.y = f2bf(o1 * inv);
  r.z = f2bf(o2 * inv); r.w = f2bf(o3 * inv);
  *(ushort4*)(ctx + (size_t)q * D + d0) = r;
}

// ------------------------------- launch ----------------------------------
extern "C" void kernel_launch(void* const* d_in, const int* in_sizes, int n_in,
                              void* d_out, int out_size, void* d_ws, size_t ws_size,
                              hipStream_t stream) {
  const float* x    = (const float*)d_in[0];
  const float* abias= (const float*)d_in[1];
  const float* ln1g = (const float*)d_in[2];
  const float* ln1b = (const float*)d_in[3];
  const float* wq   = (const float*)d_in[4];
  const float* bq   = (const float*)d_in[5];
  const float* wk   = (const float*)d_in[6];
  const float* bk   = (const float*)d_in[7];
  const float* wv   = (const float*)d_in[8];
  const float* bv   = (const float*)d_in[9];
  const float* wo   = (const float*)d_in[10];
  const float* bo   = (const float*)d_in[11];
  const float* ln2g = (const float*)d_in[12];
  const float* ln2b = (const float*)d_in[13];
  const float* w1   = (const float*)d_in[14];
  const float* b1   = (const float*)d_in[15];
  const float* w2   = (const float*)d_in[16];
  const float* b2   = (const float*)d_in[17];
  float* out = (float*)d_out;

  char* ws = (char*)d_ws;
  size_t off = 0;
  auto alloc = [&](size_t bytes) { size_t o = off; off = (off + bytes + 255) & ~(size_t)255; return (void*)(ws + o); };
  u16*   xn    = (u16*)alloc((size_t)N * D * 2);
  u16*   qkv   = (u16*)alloc((size_t)N * QKVW * 2);
  u16*   ktl   = (u16*)alloc((size_t)N * D * 2);
  u16*   vtl   = (u16*)alloc((size_t)N * D * 2);
  u16*   ctx   = (u16*)alloc((size_t)N * D * 2);
  float* x2    = (float*)alloc((size_t)N * D * 4);
  u16*   xn2   = (u16*)alloc((size_t)N * D * 2);
  u16*   hb    = (u16*)alloc((size_t)N * F * 2);
  u16*   WqkvT = (u16*)alloc((size_t)QKVW * D * 2);
  u16*   WoT   = (u16*)alloc((size_t)D * D * 2);
  u16*   W1T   = (u16*)alloc((size_t)F * D * 2);
  u16*   W2T   = (u16*)alloc((size_t)D * F * 2);
  float* bqkv  = (float*)alloc((size_t)QKVW * 4);
  u16*   ctxp  = (u16*)alloc((size_t)MS * N * D * 2);     // 16 MB bf16 partials
  float* ml    = (float*)alloc((size_t)MS * N * H * 2 * 4);

  hipFuncSetAttribute((const void*)attn_kernel,
                      hipFuncAttributeMaxDynamicSharedMemorySize, ATTN_LDS);

  // weight prep: ONE transpose launch + bias pack
  transpose_all<<<3072, 256, 0, stream>>>(wq, wk, wv, wo, w1, w2,
                                          WqkvT, WoT, W1T, W2T);
  pack_bqkv<<<(QKVW + 255) / 256, 256, 0, stream>>>(bq, bk, bv, bqkv);

  // LN1 -> QKV
  ln_kernel<<<N / 4, 256, 0, stream>>>(x, ln1g, ln1b, xn);
  gemm_bt<0><<<dim3(QKVW / 128, N / 128), 256, 0, stream>>>(xn, WqkvT, bqkv, nullptr, qkv, N, QKVW, D);
  // K/V fragment tiles (one launch)
  make_kvtiles<<<2048, 256, 0, stream>>>(qkv, ktl, vtl);
  // attention: 256 blocks (XCD-mapped), then merge
  attn_kernel<<<(N / QT) * MS, 512, ATTN_LDS, stream>>>(qkv, ktl, vtl, abias, ctxp, ml);
  attn_merge<<<(N * 128) / 256, 256, 0, stream>>>(ctxp, ml, ctx);
  // O proj + residual -> x2 (fp32), full-occupancy BM=64
  gemm_bt64<<<dim3(D / 128, N / 64), 256, 0, stream>>>(ctx, WoT, bo, x, x2, N, D, D);
  // LN2 -> FFN
  ln_kernel<<<N / 4, 256, 0, stream>>>(x2, ln2g, ln2b, xn2);
  gemm_bt<1><<<dim3(F / 128, N / 128), 256, 0, stream>>>(xn2, W1T, b1, nullptr, hb, N, F, D);
  gemm_bt64<<<dim3(D / 128, N / 64), 256, 0, stream>>>(hb, W2T, b2, x2, out, N, D, F);
  (void)in_sizes; (void)n_in; (void)out_size; (void)ws_size;
}